// Round 8
// baseline (273.838 us; speedup 1.0000x reference)
//
#include <hip/hip_runtime.h>
#include <math.h>

// ---------- types ----------
using short8  = __attribute__((ext_vector_type(8))) short;   // 8 x bf16 (4 VGPRs)
using floatx4 = __attribute__((ext_vector_type(4))) float;   // MFMA accumulator

#define DEVI __device__ __forceinline__

// Problem constants
#define BATCH 2
#define SEQ   4096
#define NE    512      // n_embd
#define NH    8
#define HD    64
#define MTOT  8192     // BATCH*SEQ

// softmax scale with log2(e) folded: (1/sqrt(64)) * log2(e)
#define QSCALE 0.18033688011112042f

DEVI short f2bf(float f) {
    unsigned u = __builtin_bit_cast(unsigned, f);
    unsigned r = (u + 0x7fffu + ((u >> 16) & 1u)) >> 16;   // RNE
    return (short)r;
}

DEVI void async16(const void* g, void* l) {
    __builtin_amdgcn_global_load_lds(
        (const __attribute__((address_space(1))) void*)g,
        (__attribute__((address_space(3))) void*)l, 16, 0, 0);
}

// ---------- fused fp32 -> bf16 conversion (x + 4 weights, one dispatch) ----------
// float4-region map: [0, 1048576) = x ; then 65536 per weight (NE*NE/4 = 65536).
__global__ __launch_bounds__(256) void cvt_all(const float* __restrict__ x,
                                               const float* __restrict__ wq,
                                               const float* __restrict__ wk,
                                               const float* __restrict__ wv,
                                               const float* __restrict__ wp,
                                               short* __restrict__ xbf,
                                               short* __restrict__ wbf) {
    int i = blockIdx.x * 256 + threadIdx.x;          // 0 .. 1310719 (exact)
    const float* src; short* dst; int off;
    if (i < MTOT * NE / 4) {
        src = x; dst = xbf; off = i;
    } else {
        int j = i - MTOT * NE / 4;
        int wsel = j >> 16;                          // 65536 float4 per weight
        off = j & 65535;
        src = (wsel == 0) ? wq : (wsel == 1) ? wk : (wsel == 2) ? wv : wp;
        dst = wbf + (size_t)wsel * NE * NE;
    }
    float4 f = ((const float4*)src)[off];
    short4 o;
    o.x = f2bf(f.x); o.y = f2bf(f.y); o.z = f2bf(f.z); o.w = f2bf(f.w);
    ((short4*)dst)[off] = o;
}

// ---------- shared GEMM mainloop: C[m,n] = sum_k A[m,k] * W[n,k] ----------
// 128x128 tile, BK=64, 256 threads = 4 waves (2x2), each wave 64x64 via 4x4 MFMAs.
DEVI void gemm_mainloop(const short* __restrict__ A, const short* __restrict__ W,
                        int m0, int n0, short* ldsA, short* ldsW, floatx4 (&acc)[4][4]) {
    const int tid  = threadIdx.x;
    const int lane = tid & 63;
    const int w    = tid >> 6;
    const int wm   = w >> 1, wn = w & 1;
    const int quad = lane >> 4, l15 = lane & 15;
    const int srow = lane >> 3, scol = (lane & 7) * 8;

    for (int i = 0; i < 4; ++i)
        for (int j = 0; j < 4; ++j)
            acc[i][j] = floatx4{0.f, 0.f, 0.f, 0.f};

    for (int kt = 0; kt < NE / 64; ++kt) {
        const int k0 = kt * 64;
        for (int c = 0; c < 4; ++c) {
            const int rb = w * 32 + c * 8;
            async16(A + (size_t)(m0 + rb + srow) * NE + k0 + scol, ldsA + rb * 64);
            async16(W + (size_t)(n0 + rb + srow) * NE + k0 + scol, ldsW + rb * 64);
        }
        __syncthreads();
        for (int ks = 0; ks < 2; ++ks) {
            short8 af[4], bf[4];
            for (int i = 0; i < 4; ++i)
                af[i] = *(const short8*)(ldsA + (wm * 64 + i * 16 + l15) * 64 + ks * 32 + quad * 8);
            for (int j = 0; j < 4; ++j)
                bf[j] = *(const short8*)(ldsW + (wn * 64 + j * 16 + l15) * 64 + ks * 32 + quad * 8);
            for (int i = 0; i < 4; ++i)
                for (int j = 0; j < 4; ++j)
                    acc[i][j] = __builtin_amdgcn_mfma_f32_16x16x32_bf16(af[i], bf[j], acc[i][j], 0, 0, 0);
        }
        __syncthreads();
    }
}

// ---------- QKV GEMM ----------
// z==0: q (pre-scaled by QSCALE), z==1: k, z==2: v — all [B,H,T,HD], coalesced.
__global__ __launch_bounds__(256) void gemm_qkv(const short* __restrict__ xbf,
                                                const short* __restrict__ wbf,
                                                const float* __restrict__ bq,
                                                const float* __restrict__ bk,
                                                const float* __restrict__ bv,
                                                short* __restrict__ qkv) {
    __shared__ short ldsA[128 * 64];
    __shared__ short ldsW[128 * 64];
    const int m0 = blockIdx.x * 128, n0 = blockIdx.y * 128, z = blockIdx.z;
    const short* W = wbf + (size_t)z * (NE * NE);
    const float* bias = (z == 0) ? bq : (z == 1) ? bk : bv;
    short* out = qkv + (size_t)z * (MTOT * NE);

    floatx4 acc[4][4];
    gemm_mainloop(xbf, W, m0, n0, ldsA, ldsW, acc);

    const int lane = threadIdx.x & 63, w = threadIdx.x >> 6;
    const int wm = w >> 1, wn = w & 1, quad = lane >> 4, l15 = lane & 15;
    const float scale = (z == 0) ? QSCALE : 1.0f;
    for (int j = 0; j < 4; ++j) {
        const int col = n0 + wn * 64 + j * 16 + l15;
        const float bz = bias[col];
        const int h = col >> 6, d = col & 63;
        for (int i = 0; i < 4; ++i) {
            for (int r = 0; r < 4; ++r) {
                const int row = m0 + wm * 64 + i * 16 + quad * 4 + r;
                const int b = row >> 12, t = row & 4095;
                const float v = (acc[i][j][r] + bz) * scale;
                out[(((size_t)(b * NH + h)) * SEQ + t) * HD + d] = f2bf(v);
            }
        }
    }
}

// ---------- V transpose: vb[bh][t][d] -> vt[bh][d][t] ----------
__global__ __launch_bounds__(256) void transpose_v(const short* __restrict__ vb,
                                                   short* __restrict__ vt) {
    const int bh = blockIdx.y;
    const int t0 = blockIdx.x * 64;
    __shared__ short tile[64 * 66];
    const int tid = threadIdx.x;
    const int r  = tid >> 3;              // 0..31
    const int c8 = tid & 7;               // 0..7

    const short* src = vb + ((size_t)bh * SEQ + t0) * HD;
#pragma unroll
    for (int p = 0; p < 2; ++p) {
        const int row = p * 32 + r;       // t-local
        short8 v = *(const short8*)&src[row * HD + c8 * 8];
#pragma unroll
        for (int i = 0; i < 8; ++i)
            tile[row * 66 + c8 * 8 + i] = v[i];
    }
    __syncthreads();

    short* dst = vt + (size_t)bh * (HD * SEQ) + t0;
#pragma unroll
    for (int p = 0; p < 2; ++p) {
        const int d = p * 32 + r;
        short8 o;
#pragma unroll
        for (int i = 0; i < 8; ++i)
            o[i] = tile[(c8 * 8 + i) * 66 + d];
        *(short8*)&dst[(size_t)d * SEQ + c8 * 8] = o;
    }
}

// ---------- projection GEMM: fp32 out [MTOT, NE] ----------
__global__ __launch_bounds__(256) void gemm_proj(const short* __restrict__ ybf,
                                                 const short* __restrict__ wp,
                                                 const float* __restrict__ bp,
                                                 float* __restrict__ out) {
    __shared__ short ldsA[128 * 64];
    __shared__ short ldsW[128 * 64];
    const int m0 = blockIdx.x * 128, n0 = blockIdx.y * 128;

    floatx4 acc[4][4];
    gemm_mainloop(ybf, wp, m0, n0, ldsA, ldsW, acc);

    const int lane = threadIdx.x & 63, w = threadIdx.x >> 6;
    const int wm = w >> 1, wn = w & 1, quad = lane >> 4, l15 = lane & 15;
    for (int j = 0; j < 4; ++j) {
        const int col = n0 + wn * 64 + j * 16 + l15;
        const float bz = bp[col];
        for (int i = 0; i < 4; ++i) {
            for (int r = 0; r < 4; ++r) {
                const int row = m0 + wm * 64 + i * 16 + quad * 4 + r;
                out[(size_t)row * NE + col] = acc[i][j][r] + bz;
            }
        }
    }
}

// ---------- flash attention (causal) ----------
// R7 post-mortem: tr_read P-path REFUTED on HW (absmax 166) — its real semantics
// are 128B-aligned-tile + column-from-addr%128, not a per-lane stride gather.
// P-path reverted to the R5-verified f2bf/b16-write/b128-read round-trip.
// R8 structure (this round): attack the confirmed latency-bound regime
// (MfmaUtil 18%, occ 19% at exactly grid 512 = 2 blocks/CU):
//  - V staging DROPPED (m169 pattern): K/V per bh = 1MB, all blocks of a bh
//    pinned to one XCD -> L2-resident; vf read direct from vt, 16B/lane,
//    issued EARLY so ~200cy L2 latency hides under QK+softmax. LDS 74.75->41KB.
//  - grid 512 -> 1024 (one qt per block) + __launch_bounds__(256,3): 3 blocks/CU
//    resident (+50% waves/SIMD). qt = 63-(id>>4): longest blocks dispatch first,
//    backfill absorbs causal imbalance. bh map keeps same-bh on same XCD.
//  - hot loop stays R5: branch-free full windows, diagonal peeled (DOMASK),
//    subtiles straight-line, K dbuf staged via async16.
// P-pack MUST be f2bf (RNE): truncating pack failed 4-for-4. Do not retry.
// T5 setprio kept around MFMA clusters (m191 regime).
template<bool DOMASK>
DEVI void attn_subtile(const short* __restrict__ bK, const short* __restrict__ Vg,
                       const short8 (&qfrag)[2], short* __restrict__ myP,
                       floatx4 (&O)[4], float (&lsum)[4],
                       const int p0, const int p1, const int quad, const int l15,
                       const int w) {
    // V fragments direct from global (L2-resident): issue FIRST so the load
    // latency hides under kf reads + QK + softmax (consumed only at PV).
    short8 vf[2][4];
#pragma unroll
    for (int ks = 0; ks < 2; ++ks)
#pragma unroll
        for (int n = 0; n < 4; ++n)
            vf[ks][n] = *(const short8*)&Vg[(size_t)(n * 16 + l15) * SEQ + ks * 32 + quad * 8];

    short8 kf[2][4];
#pragma unroll
    for (int n = 0; n < 4; ++n) {
        const int row = n * 16 + l15;
        kf[0][n] = *(const short8*)(bK + row * 64 + p0 * 8);
        kf[1][n] = *(const short8*)(bK + row * 64 + p1 * 8);
    }

    floatx4 S[4];
#pragma unroll
    for (int n = 0; n < 4; ++n) S[n] = floatx4{0.f, 0.f, 0.f, 0.f};
    __builtin_amdgcn_s_setprio(1);
#pragma unroll
    for (int ks = 0; ks < 2; ++ks)
#pragma unroll
        for (int n = 0; n < 4; ++n)
            S[n] = __builtin_amdgcn_mfma_f32_16x16x32_bf16(qfrag[ks], kf[ks][n], S[n], 0, 0, 0);
    __builtin_amdgcn_s_setprio(0);

    if (DOMASK) {
        // causal mask on the diagonal subtile (exp2(-3e38) = 0)
#pragma unroll
        for (int n = 0; n < 4; ++n)
#pragma unroll
            for (int r = 0; r < 4; ++r) {
                const int rowl = w * 16 + quad * 4 + r;
                const int coll = n * 16 + l15;
                if (coll > rowl) S[n][r] = -3.0e38f;
            }
    }

    // no-max softmax: P = exp2(S); deferred row-sum partials
#pragma unroll
    for (int n = 0; n < 4; ++n)
#pragma unroll
        for (int r = 0; r < 4; ++r)
            S[n][r] = __builtin_amdgcn_exp2f(S[n][r]);
#pragma unroll
    for (int r = 0; r < 4; ++r)
        lsum[r] += (S[0][r] + S[1][r]) + (S[2][r] + S[3][r]);

    // P (C/D layout) -> wave-private LDS (stride 72), RNE pack (f2bf).
#pragma unroll
    for (int n = 0; n < 4; ++n)
#pragma unroll
        for (int r = 0; r < 4; ++r)
            myP[(quad * 4 + r) * 72 + n * 16 + l15] = f2bf(S[n][r]);

    short8 pf[2];
#pragma unroll
    for (int ks = 0; ks < 2; ++ks)
        pf[ks] = *(const short8*)(myP + l15 * 72 + ks * 32 + quad * 8);

    // O += P @ V
    __builtin_amdgcn_s_setprio(1);
#pragma unroll
    for (int ks = 0; ks < 2; ++ks)
#pragma unroll
        for (int n = 0; n < 4; ++n)
            O[n] = __builtin_amdgcn_mfma_f32_16x16x32_bf16(pf[ks], vf[ks][n], O[n], 0, 0, 0);
    __builtin_amdgcn_s_setprio(0);
}

__global__ __launch_bounds__(256, 3) void attn(const short* __restrict__ q,
                                               const short* __restrict__ k,
                                               const short* __restrict__ vt,
                                               short* __restrict__ y) {
    const int id = blockIdx.x;                 // 0..1023
    const int qt = 63 - (id >> 4);             // longest blocks dispatched first
    const int bh = ((id & 7) << 1) | ((id >> 3) & 1);   // same bh -> same XCD
    const int tid = threadIdx.x, lane = tid & 63, w = tid >> 6;
    const int quad = lane >> 4, l15 = lane & 15;

    __shared__ short ldsK[2][2][64 * 64];   // [pipe][sub], swizzled (32 KB)
    __shared__ short ldsP[4][16 * 72];      // per-wave P round-trip, stride 72

    const short* K  = k  + (size_t)bh * (SEQ * HD);
    const short* VT = vt + (size_t)bh * (HD * SEQ);
    short* myP = (short*)ldsP[w];
    const int b = bh >> 3, h = bh & 7;

    // staging: lane l of chunk c covers row j = c*8 + (l>>3), phys block l&7,
    // logical block lb = ((l&7) - (l>>3)) & 7.
    const int lb   = ((lane & 7) - (lane >> 3)) & 7;
    const int jrow = lane >> 3;
    // fragment reads: row = n*16+l15, logical block ks*4+quad ->
    // phys = (quad + (l15&7)) & 7  xor (ks*4)
    const int p0 = (quad + (l15 & 7)) & 7;
    const int p1 = p0 ^ 4;

    const short* Q = q + (size_t)bh * (SEQ * HD) + (size_t)qt * 64 * HD;

    short8 qfrag[2];
#pragma unroll
    for (int ks = 0; ks < 2; ++ks)
        qfrag[ks] = *(const short8*)&Q[(w * 16 + l15) * HD + ks * 32 + quad * 8];

    floatx4 O[4];
    float lsum[4];
#pragma unroll
    for (int n = 0; n < 4; ++n) O[n] = floatx4{0.f, 0.f, 0.f, 0.f};
#pragma unroll
    for (int r = 0; r < 4; ++r) lsum[r] = 0.f;

    const int npair = (qt >> 1) + 1;    // key windows; window p holds jt=2p,2p+1
    // K staging is unconditional: max staged js = 2*npair-1 <= 63 for all qt;
    // windows whose jt exceeds qt are staged but never computed.

    // stage window 0 K (both subtiles)
#pragma unroll
    for (int s = 0; s < 2; ++s) {
        const short* Kt = K + (size_t)s * 64 * HD;
#pragma unroll
        for (int c2 = 0; c2 < 2; ++c2) {
            const int chunk = w * 2 + c2;
            const int j = chunk * 8 + jrow;
            async16(Kt + (size_t)j * HD + lb * 8, ldsK[0][s] + chunk * 512);
        }
    }

    // ---- main loop: FULL windows only (branch-free, mask-free) ----
    for (int p = 0; p + 1 < npair; ++p) {
        __syncthreads();                // drains the async stage of this window
        const int pipe = p & 1, nx = pipe ^ 1;

        // stage window p+1 K into the other pipe (lands during this compute)
#pragma unroll
        for (int s = 0; s < 2; ++s) {
            const int js = 2 * (p + 1) + s;
            const short* Kt = K + (size_t)js * 64 * HD;
#pragma unroll
            for (int c2 = 0; c2 < 2; ++c2) {
                const int chunk = w * 2 + c2;
                const int j = chunk * 8 + jrow;
                async16(Kt + (size_t)j * HD + lb * 8, ldsK[nx][s] + chunk * 512);
            }
        }

        // two subtiles, straight-line: scheduler interleaves the chains
        attn_subtile<false>(ldsK[pipe][0], VT + (2 * p) * 64, qfrag, myP, O, lsum,
                            p0, p1, quad, l15, w);
        attn_subtile<false>(ldsK[pipe][1], VT + (2 * p + 1) * 64, qfrag, myP, O, lsum,
                            p0, p1, quad, l15, w);
    }

    // ---- epilogue window p = npair-1 (holds the diagonal) ----
    {
        __syncthreads();
        const int ep = (npair - 1) & 1;
        if (qt & 1) {
            // jt = qt-1 (full) then jt = qt (diagonal)
            attn_subtile<false>(ldsK[ep][0], VT + (qt - 1) * 64, qfrag, myP, O, lsum,
                                p0, p1, quad, l15, w);
            attn_subtile<true >(ldsK[ep][1], VT + qt * 64, qfrag, myP, O, lsum,
                                p0, p1, quad, l15, w);
        } else {
            // jt = qt (diagonal); sub1 staged but skipped
            attn_subtile<true >(ldsK[ep][0], VT + qt * 64, qfrag, myP, O, lsum,
                                p0, p1, quad, l15, w);
        }
    }

    // reduce row-sum partials across the 16-lane row group
#pragma unroll
    for (int r = 0; r < 4; ++r) {
#pragma unroll
        for (int off = 1; off < 16; off <<= 1)
            lsum[r] += __shfl_xor(lsum[r], off, 64);
    }

    // epilogue: y[b, t, h*64+d] bf16, normalized by lsum
#pragma unroll
    for (int r = 0; r < 4; ++r) {
        const float inv = 1.0f / lsum[r];
        const int t = qt * 64 + w * 16 + quad * 4 + r;
#pragma unroll
        for (int n = 0; n < 4; ++n) {
            const int col = h * 64 + n * 16 + l15;
            y[((size_t)(b * SEQ + t)) * NE + col] = f2bf(O[n][r] * inv);
        }
    }
}

// ---------- host launch ----------
extern "C" void kernel_launch(void* const* d_in, const int* in_sizes, int n_in,
                              void* d_out, int out_size, void* d_ws, size_t ws_size,
                              hipStream_t stream) {
    const float* x  = (const float*)d_in[0];
    const float* Wq = (const float*)d_in[3];
    const float* bq = (const float*)d_in[4];
    const float* Wk = (const float*)d_in[5];
    const float* bk = (const float*)d_in[6];
    const float* Wv = (const float*)d_in[7];
    const float* bv = (const float*)d_in[8];
    const float* Wp = (const float*)d_in[9];
    const float* bp = (const float*)d_in[10];
    float* out = (float*)d_out;

    // ws layout (shorts) with live-range aliasing — peak 17.8M shorts = 35.6 MB
    // (>44 MB failed in R7; keep peak at or below this proven level)
    short* ws   = (short*)d_ws;
    short* xbf  = ws;                           // 8192*512 shorts
    short* wbf  = xbf + (size_t)MTOT * NE;      // 4 * 512*512
    short* qb   = wbf + 4 * (size_t)NE * NE;    // q  [B,H,T,HD]  (pre-scaled)
    short* kb   = qb + (size_t)MTOT * NE;       // k  [B,H,T,HD]
    short* vb   = kb + (size_t)MTOT * NE;       // v  [B,H,T,HD]
    short* vtb  = xbf;                          // v^T [B,H,HD,T]  (aliases xbf)
    short* yb   = vb;                           // y   [B,T,C]     (aliases vb)

    // fused conversion: x + 4 weights, one dispatch (5120 blocks, exact cover)
    cvt_all<<<dim3((MTOT * NE / 4 + 4 * NE * NE / 4) / 256), 256, 0, stream>>>(
        x, Wq, Wk, Wv, Wp, xbf, wbf);

    gemm_qkv<<<dim3(MTOT / 128, NE / 128, 3), 256, 0, stream>>>(xbf, wbf, bq, bk, bv, qb);

    transpose_v<<<dim3(SEQ / 64, BATCH * NH), 256, 0, stream>>>(vb, vtb);

    attn<<<dim3(1024), 256, 0, stream>>>(qb, kb, vtb, yb);

    gemm_proj<<<dim3(MTOT / 128, NE / 128), 256, 0, stream>>>(yb, wbf + 3 * (size_t)NE * NE, bp, out);
}

// Round 10
// 224.958 us; speedup vs baseline: 1.2173x; 1.2173x over previous
//
#include <hip/hip_runtime.h>
#include <math.h>

// ---------- types ----------
using short8  = __attribute__((ext_vector_type(8))) short;   // 8 x bf16 (4 VGPRs)
using floatx4 = __attribute__((ext_vector_type(4))) float;   // MFMA accumulator

#define DEVI __device__ __forceinline__

// Problem constants
#define BATCH 2
#define SEQ   4096
#define NE    512      // n_embd
#define NH    8
#define HD    64
#define MTOT  8192     // BATCH*SEQ

// softmax scale with log2(e) folded: (1/sqrt(64)) * log2(e)
#define QSCALE 0.18033688011112042f

DEVI short f2bf(float f) {
    unsigned u = __builtin_bit_cast(unsigned, f);
    unsigned r = (u + 0x7fffu + ((u >> 16) & 1u)) >> 16;   // RNE
    return (short)r;
}

DEVI void async16(const void* g, void* l) {
    __builtin_amdgcn_global_load_lds(
        (const __attribute__((address_space(1))) void*)g,
        (__attribute__((address_space(3))) void*)l, 16, 0, 0);
}

// ---------- fused fp32 -> bf16 conversion (x + 4 weights, one dispatch) ----------
// float4-region map: [0, 1048576) = x ; then 65536 per weight (NE*NE/4 = 65536).
__global__ __launch_bounds__(256) void cvt_all(const float* __restrict__ x,
                                               const float* __restrict__ wq,
                                               const float* __restrict__ wk,
                                               const float* __restrict__ wv,
                                               const float* __restrict__ wp,
                                               short* __restrict__ xbf,
                                               short* __restrict__ wbf) {
    int i = blockIdx.x * 256 + threadIdx.x;          // 0 .. 1310719 (exact)
    const float* src; short* dst; int off;
    if (i < MTOT * NE / 4) {
        src = x; dst = xbf; off = i;
    } else {
        int j = i - MTOT * NE / 4;
        int wsel = j >> 16;                          // 65536 float4 per weight
        off = j & 65535;
        src = (wsel == 0) ? wq : (wsel == 1) ? wk : (wsel == 2) ? wv : wp;
        dst = wbf + (size_t)wsel * NE * NE;
    }
    float4 f = ((const float4*)src)[off];
    short4 o;
    o.x = f2bf(f.x); o.y = f2bf(f.y); o.z = f2bf(f.z); o.w = f2bf(f.w);
    ((short4*)dst)[off] = o;
}

// ---------- shared GEMM mainloop: C[m,n] = sum_k A[m,k] * W[n,k] ----------
// 128x128 tile, BK=64, 256 threads = 4 waves (2x2), each wave 64x64 via 4x4 MFMAs.
DEVI void gemm_mainloop(const short* __restrict__ A, const short* __restrict__ W,
                        int m0, int n0, short* ldsA, short* ldsW, floatx4 (&acc)[4][4]) {
    const int tid  = threadIdx.x;
    const int lane = tid & 63;
    const int w    = tid >> 6;
    const int wm   = w >> 1, wn = w & 1;
    const int quad = lane >> 4, l15 = lane & 15;
    const int srow = lane >> 3, scol = (lane & 7) * 8;

    for (int i = 0; i < 4; ++i)
        for (int j = 0; j < 4; ++j)
            acc[i][j] = floatx4{0.f, 0.f, 0.f, 0.f};

    for (int kt = 0; kt < NE / 64; ++kt) {
        const int k0 = kt * 64;
        for (int c = 0; c < 4; ++c) {
            const int rb = w * 32 + c * 8;
            async16(A + (size_t)(m0 + rb + srow) * NE + k0 + scol, ldsA + rb * 64);
            async16(W + (size_t)(n0 + rb + srow) * NE + k0 + scol, ldsW + rb * 64);
        }
        __syncthreads();
        for (int ks = 0; ks < 2; ++ks) {
            short8 af[4], bf[4];
            for (int i = 0; i < 4; ++i)
                af[i] = *(const short8*)(ldsA + (wm * 64 + i * 16 + l15) * 64 + ks * 32 + quad * 8);
            for (int j = 0; j < 4; ++j)
                bf[j] = *(const short8*)(ldsW + (wn * 64 + j * 16 + l15) * 64 + ks * 32 + quad * 8);
            for (int i = 0; i < 4; ++i)
                for (int j = 0; j < 4; ++j)
                    acc[i][j] = __builtin_amdgcn_mfma_f32_16x16x32_bf16(af[i], bf[j], acc[i][j], 0, 0, 0);
        }
        __syncthreads();
    }
}

// ---------- QKV GEMM ----------
// z==0: q (pre-scaled by QSCALE), z==1: k, z==2: v — all [B,H,T,HD], coalesced.
__global__ __launch_bounds__(256) void gemm_qkv(const short* __restrict__ xbf,
                                                const short* __restrict__ wbf,
                                                const float* __restrict__ bq,
                                                const float* __restrict__ bk,
                                                const float* __restrict__ bv,
                                                short* __restrict__ qkv) {
    __shared__ short ldsA[128 * 64];
    __shared__ short ldsW[128 * 64];
    const int m0 = blockIdx.x * 128, n0 = blockIdx.y * 128, z = blockIdx.z;
    const short* W = wbf + (size_t)z * (NE * NE);
    const float* bias = (z == 0) ? bq : (z == 1) ? bk : bv;
    short* out = qkv + (size_t)z * (MTOT * NE);

    floatx4 acc[4][4];
    gemm_mainloop(xbf, W, m0, n0, ldsA, ldsW, acc);

    const int lane = threadIdx.x & 63, w = threadIdx.x >> 6;
    const int wm = w >> 1, wn = w & 1, quad = lane >> 4, l15 = lane & 15;
    const float scale = (z == 0) ? QSCALE : 1.0f;
    for (int j = 0; j < 4; ++j) {
        const int col = n0 + wn * 64 + j * 16 + l15;
        const float bz = bias[col];
        const int h = col >> 6, d = col & 63;
        for (int i = 0; i < 4; ++i) {
            for (int r = 0; r < 4; ++r) {
                const int row = m0 + wm * 64 + i * 16 + quad * 4 + r;
                const int b = row >> 12, t = row & 4095;
                const float v = (acc[i][j][r] + bz) * scale;
                out[(((size_t)(b * NH + h)) * SEQ + t) * HD + d] = f2bf(v);
            }
        }
    }
}

// ---------- V transpose: vb[bh][t][d] -> vt[bh][d][t] ----------
__global__ __launch_bounds__(256) void transpose_v(const short* __restrict__ vb,
                                                   short* __restrict__ vt) {
    const int bh = blockIdx.y;
    const int t0 = blockIdx.x * 64;
    __shared__ short tile[64 * 66];
    const int tid = threadIdx.x;
    const int r  = tid >> 3;              // 0..31
    const int c8 = tid & 7;               // 0..7

    const short* src = vb + ((size_t)bh * SEQ + t0) * HD;
#pragma unroll
    for (int p = 0; p < 2; ++p) {
        const int row = p * 32 + r;       // t-local
        short8 v = *(const short8*)&src[row * HD + c8 * 8];
#pragma unroll
        for (int i = 0; i < 8; ++i)
            tile[row * 66 + c8 * 8 + i] = v[i];
    }
    __syncthreads();

    short* dst = vt + (size_t)bh * (HD * SEQ) + t0;
#pragma unroll
    for (int p = 0; p < 2; ++p) {
        const int d = p * 32 + r;
        short8 o;
#pragma unroll
        for (int i = 0; i < 8; ++i)
            o[i] = tile[(c8 * 8 + i) * 66 + d];
        *(short8*)&dst[(size_t)d * SEQ + c8 * 8] = o;
    }
}

// ---------- projection GEMM: fp32 out [MTOT, NE] ----------
__global__ __launch_bounds__(256) void gemm_proj(const short* __restrict__ ybf,
                                                 const short* __restrict__ wp,
                                                 const float* __restrict__ bp,
                                                 float* __restrict__ out) {
    __shared__ short ldsA[128 * 64];
    __shared__ short ldsW[128 * 64];
    const int m0 = blockIdx.x * 128, n0 = blockIdx.y * 128;

    floatx4 acc[4][4];
    gemm_mainloop(ybf, wp, m0, n0, ldsA, ldsW, acc);

    const int lane = threadIdx.x & 63, w = threadIdx.x >> 6;
    const int wm = w >> 1, wn = w & 1, quad = lane >> 4, l15 = lane & 15;
    for (int j = 0; j < 4; ++j) {
        const int col = n0 + wn * 64 + j * 16 + l15;
        const float bz = bp[col];
        for (int i = 0; i < 4; ++i) {
            for (int r = 0; r < 4; ++r) {
                const int row = m0 + wm * 64 + i * 16 + quad * 4 + r;
                out[(size_t)row * NE + col] = acc[i][j][r] + bz;
            }
        }
    }
}

// ---------- flash attention (causal) ----------
// R9 post-mortem: swapped-QK in-register P REFUTED on HW (NaN) despite
// paper-consistent algebra — the in-register P-path family (tr_read R7,
// swapped-QK R9) is SHELVED; the verified P-path is f2bf + stride-72 LDS
// round-trip (R5, 5-for-5 correct, 79us).
// R10: attn body = R5 verbatim, but split into TWO dispatches (part=0/1) so
// the GEMM/cvt kernels finally surface in rocprof top-5 (attn monopolized it).
// Balanced mapping: part0 qt in {0..15}u{48..63}, part1 {16..47}; co-resident
// blocks (id, id+256) pair to qt-sum 63 -> equal CU load, equal dispatch work.
// P-pack MUST be f2bf (RNE): truncating pack failed 4-for-4. Do not retry.
// T5 setprio kept around MFMA clusters (m191 regime).
template<bool DOMASK>
DEVI void attn_subtile(const short* __restrict__ bK, const short* __restrict__ bV,
                       const short8 (&qfrag)[2], short* __restrict__ myP,
                       floatx4 (&O)[4], float (&lsum)[4],
                       const int p0, const int p1, const int quad, const int l15,
                       const int w) {
    short8 kf[2][4], vf[2][4];
#pragma unroll
    for (int n = 0; n < 4; ++n) {
        const int row = n * 16 + l15;
        kf[0][n] = *(const short8*)(bK + row * 64 + p0 * 8);
        kf[1][n] = *(const short8*)(bK + row * 64 + p1 * 8);
        vf[0][n] = *(const short8*)(bV + row * 64 + p0 * 8);
        vf[1][n] = *(const short8*)(bV + row * 64 + p1 * 8);
    }

    floatx4 S[4];
#pragma unroll
    for (int n = 0; n < 4; ++n) S[n] = floatx4{0.f, 0.f, 0.f, 0.f};
    __builtin_amdgcn_s_setprio(1);
#pragma unroll
    for (int ks = 0; ks < 2; ++ks)
#pragma unroll
        for (int n = 0; n < 4; ++n)
            S[n] = __builtin_amdgcn_mfma_f32_16x16x32_bf16(qfrag[ks], kf[ks][n], S[n], 0, 0, 0);
    __builtin_amdgcn_s_setprio(0);

    if (DOMASK) {
        // causal mask on the diagonal subtile (exp2(-3e38) = 0)
#pragma unroll
        for (int n = 0; n < 4; ++n)
#pragma unroll
            for (int r = 0; r < 4; ++r) {
                const int rowl = w * 16 + quad * 4 + r;
                const int coll = n * 16 + l15;
                if (coll > rowl) S[n][r] = -3.0e38f;
            }
    }

    // no-max softmax: P = exp2(S); deferred row-sum partials
#pragma unroll
    for (int n = 0; n < 4; ++n)
#pragma unroll
        for (int r = 0; r < 4; ++r)
            S[n][r] = __builtin_amdgcn_exp2f(S[n][r]);
#pragma unroll
    for (int r = 0; r < 4; ++r)
        lsum[r] += (S[0][r] + S[1][r]) + (S[2][r] + S[3][r]);

    // P (C/D layout) -> wave-private LDS (stride 72), RNE pack (f2bf).
#pragma unroll
    for (int n = 0; n < 4; ++n)
#pragma unroll
        for (int r = 0; r < 4; ++r)
            myP[(quad * 4 + r) * 72 + n * 16 + l15] = f2bf(S[n][r]);

    short8 pf[2];
#pragma unroll
    for (int ks = 0; ks < 2; ++ks)
        pf[ks] = *(const short8*)(myP + l15 * 72 + ks * 32 + quad * 8);

    // O += P @ V
    __builtin_amdgcn_s_setprio(1);
#pragma unroll
    for (int ks = 0; ks < 2; ++ks)
#pragma unroll
        for (int n = 0; n < 4; ++n)
            O[n] = __builtin_amdgcn_mfma_f32_16x16x32_bf16(pf[ks], vf[ks][n], O[n], 0, 0, 0);
    __builtin_amdgcn_s_setprio(0);
}

__global__ __launch_bounds__(256, 2) void attn(const short* __restrict__ q,
                                               const short* __restrict__ k,
                                               const short* __restrict__ vt,
                                               short* __restrict__ y,
                                               const int part) {
    const int id = blockIdx.x;                 // 0..511
    const int u  = id >> 4;                    // 0..31
    // balanced split: co-resident blocks (id, id+256) get qt-sum 63.
    // part 0: qt in {0..15} u {48..63}; part 1: qt in {16..47}.
    const int qt = (id < 256) ? (part * 16 + u) : (63 - part * 16 - (u - 16));
    const int bh = ((id & 7) << 1) | ((id >> 3) & 1);
    const int tid = threadIdx.x, lane = tid & 63, w = tid >> 6;
    const int quad = lane >> 4, l15 = lane & 15;

    __shared__ short ldsK[2][2][64 * 64];   // [pipe][sub], swizzled
    __shared__ short ldsV[2][2][64 * 64];   // [pipe][sub], swizzled
    __shared__ short ldsP[4][16 * 72];      // per-wave P round-trip, stride 72

    const short* K  = k  + (size_t)bh * (SEQ * HD);
    const short* VT = vt + (size_t)bh * (HD * SEQ);
    short* myP = (short*)ldsP[w];
    const int b = bh >> 3, h = bh & 7;

    // staging: lane l of chunk c covers row j = c*8 + (l>>3), phys block l&7,
    // logical block lb = ((l&7) - (l>>3)) & 7.
    const int lb   = ((lane & 7) - (lane >> 3)) & 7;
    const int jrow = lane >> 3;
    // fragment reads: row = n*16+l15, logical block ks*4+quad ->
    // phys = (quad + (l15&7)) & 7  xor (ks*4)
    const int p0 = (quad + (l15 & 7)) & 7;
    const int p1 = p0 ^ 4;

    const short* Q = q + (size_t)bh * (SEQ * HD) + (size_t)qt * 64 * HD;

    short8 qfrag[2];
#pragma unroll
    for (int ks = 0; ks < 2; ++ks)
        qfrag[ks] = *(const short8*)&Q[(w * 16 + l15) * HD + ks * 32 + quad * 8];

    floatx4 O[4];
    float lsum[4];
#pragma unroll
    for (int n = 0; n < 4; ++n) O[n] = floatx4{0.f, 0.f, 0.f, 0.f};
#pragma unroll
    for (int r = 0; r < 4; ++r) lsum[r] = 0.f;

    const int npair = (qt >> 1) + 1;    // key windows; window p holds jt=2p,2p+1
    // staging is unconditional everywhere: max staged js = 2*npair-1 <= 63
    // for all qt (proven), so no OOB; windows whose jt exceeds qt are staged
    // but never computed.

    // stage pair 0
#pragma unroll
    for (int s = 0; s < 2; ++s) {
        const short* Kt = K + (size_t)s * 64 * HD;
        const short* Vc = VT + s * 64;
#pragma unroll
        for (int c2 = 0; c2 < 2; ++c2) {
            const int chunk = w * 2 + c2;
            const int j = chunk * 8 + jrow;
            async16(Kt + (size_t)j * HD + lb * 8, ldsK[0][s] + chunk * 512);
            async16(Vc + (size_t)j * SEQ + lb * 8, ldsV[0][s] + chunk * 512);
        }
    }

    // ---- main loop: FULL windows only (branch-free, mask-free) ----
    for (int p = 0; p + 1 < npair; ++p) {
        __syncthreads();                // drains the async stage of this pair
        const int pipe = p & 1, nx = pipe ^ 1;

        // stage pair p+1 into the other pipe (lands during this pair's compute)
#pragma unroll
        for (int s = 0; s < 2; ++s) {
            const int js = 2 * (p + 1) + s;
            const short* Kt = K + (size_t)js * 64 * HD;
            const short* Vc = VT + js * 64;
#pragma unroll
            for (int c2 = 0; c2 < 2; ++c2) {
                const int chunk = w * 2 + c2;
                const int j = chunk * 8 + jrow;
                async16(Kt + (size_t)j * HD + lb * 8, ldsK[nx][s] + chunk * 512);
                async16(Vc + (size_t)j * SEQ + lb * 8, ldsV[nx][s] + chunk * 512);
            }
        }

        // two subtiles, straight-line: scheduler interleaves the chains
        attn_subtile<false>(ldsK[pipe][0], ldsV[pipe][0], qfrag, myP, O, lsum,
                            p0, p1, quad, l15, w);
        attn_subtile<false>(ldsK[pipe][1], ldsV[pipe][1], qfrag, myP, O, lsum,
                            p0, p1, quad, l15, w);
    }

    // ---- epilogue window p = npair-1 (holds the diagonal) ----
    {
        __syncthreads();
        const int ep = (npair - 1) & 1;
        if (qt & 1) {
            // jt = qt-1 (full) then jt = qt (diagonal)
            attn_subtile<false>(ldsK[ep][0], ldsV[ep][0], qfrag, myP, O, lsum,
                                p0, p1, quad, l15, w);
            attn_subtile<true >(ldsK[ep][1], ldsV[ep][1], qfrag, myP, O, lsum,
                                p0, p1, quad, l15, w);
        } else {
            // jt = qt (diagonal); sub1 staged but skipped
            attn_subtile<true >(ldsK[ep][0], ldsV[ep][0], qfrag, myP, O, lsum,
                                p0, p1, quad, l15, w);
        }
    }

    // reduce row-sum partials across the 16-lane row group
#pragma unroll
    for (int r = 0; r < 4; ++r) {
#pragma unroll
        for (int off = 1; off < 16; off <<= 1)
            lsum[r] += __shfl_xor(lsum[r], off, 64);
    }

    // epilogue: y[b, t, h*64+d] bf16, normalized by lsum
#pragma unroll
    for (int r = 0; r < 4; ++r) {
        const float inv = 1.0f / lsum[r];
        const int t = qt * 64 + w * 16 + quad * 4 + r;
#pragma unroll
        for (int n = 0; n < 4; ++n) {
            const int col = h * 64 + n * 16 + l15;
            y[((size_t)(b * SEQ + t)) * NE + col] = f2bf(O[n][r] * inv);
        }
    }
}

// ---------- host launch ----------
extern "C" void kernel_launch(void* const* d_in, const int* in_sizes, int n_in,
                              void* d_out, int out_size, void* d_ws, size_t ws_size,
                              hipStream_t stream) {
    const float* x  = (const float*)d_in[0];
    const float* Wq = (const float*)d_in[3];
    const float* bq = (const float*)d_in[4];
    const float* Wk = (const float*)d_in[5];
    const float* bk = (const float*)d_in[6];
    const float* Wv = (const float*)d_in[7];
    const float* bv = (const float*)d_in[8];
    const float* Wp = (const float*)d_in[9];
    const float* bp = (const float*)d_in[10];
    float* out = (float*)d_out;

    // ws layout (shorts) with live-range aliasing — peak 17.8M shorts = 35.6 MB
    short* ws   = (short*)d_ws;
    short* xbf  = ws;                           // 8192*512 shorts
    short* wbf  = xbf + (size_t)MTOT * NE;      // 4 * 512*512
    short* qb   = wbf + 4 * (size_t)NE * NE;    // q  [B,H,T,HD]  (pre-scaled)
    short* kb   = qb + (size_t)MTOT * NE;       // k  [B,H,T,HD]
    short* vb   = kb + (size_t)MTOT * NE;       // v  [B,H,T,HD]
    short* vtb  = xbf;                          // v^T [B,H,HD,T]  (aliases xbf)
    short* yb   = vb;                           // y   [B,T,C]     (aliases vb)

    // fused conversion: x + 4 weights, one dispatch (5120 blocks, exact cover)
    cvt_all<<<dim3((MTOT * NE / 4 + 4 * NE * NE / 4) / 256), 256, 0, stream>>>(
        x, Wq, Wk, Wv, Wp, xbf, wbf);

    gemm_qkv<<<dim3(MTOT / 128, NE / 128, 3), 256, 0, stream>>>(xbf, wbf, bq, bk, bv, qb);

    transpose_v<<<dim3(SEQ / 64, BATCH * NH), 256, 0, stream>>>(vb, vtb);

    attn<<<dim3(512), 256, 0, stream>>>(qb, kb, vtb, yb, 0);
    attn<<<dim3(512), 256, 0, stream>>>(qb, kb, vtb, yb, 1);

    gemm_proj<<<dim3(MTOT / 128, NE / 128), 256, 0, stream>>>(yb, wbf + 3 * (size_t)NE * NE, bp, out);
}

// Round 11
// 197.539 us; speedup vs baseline: 1.3862x; 1.1388x over previous
//
#include <hip/hip_runtime.h>
#include <math.h>

// ---------- types ----------
using short8  = __attribute__((ext_vector_type(8))) short;   // 8 x bf16 (4 VGPRs)
using floatx4 = __attribute__((ext_vector_type(4))) float;   // MFMA accumulator

#define DEVI __device__ __forceinline__

// Problem constants
#define BATCH 2
#define SEQ   4096
#define NE    512      // n_embd
#define NH    8
#define HD    64
#define MTOT  8192     // BATCH*SEQ

// softmax scale with log2(e) folded: (1/sqrt(64)) * log2(e)
#define QSCALE 0.18033688011112042f

DEVI short f2bf(float f) {
    unsigned u = __builtin_bit_cast(unsigned, f);
    unsigned r = (u + 0x7fffu + ((u >> 16) & 1u)) >> 16;   // RNE
    return (short)r;
}

DEVI void async16(const void* g, void* l) {
    __builtin_amdgcn_global_load_lds(
        (const __attribute__((address_space(1))) void*)g,
        (__attribute__((address_space(3))) void*)l, 16, 0, 0);
}

// ---------- fused fp32 -> bf16 conversion (x + 4 weights, one dispatch) ----------
// float4-region map: [0, 1048576) = x ; then 65536 per weight (NE*NE/4 = 65536).
__global__ __launch_bounds__(256) void cvt_all(const float* __restrict__ x,
                                               const float* __restrict__ wq,
                                               const float* __restrict__ wk,
                                               const float* __restrict__ wv,
                                               const float* __restrict__ wp,
                                               short* __restrict__ xbf,
                                               short* __restrict__ wbf) {
    int i = blockIdx.x * 256 + threadIdx.x;          // 0 .. 1310719 (exact)
    const float* src; short* dst; int off;
    if (i < MTOT * NE / 4) {
        src = x; dst = xbf; off = i;
    } else {
        int j = i - MTOT * NE / 4;
        int wsel = j >> 16;                          // 65536 float4 per weight
        off = j & 65535;
        src = (wsel == 0) ? wq : (wsel == 1) ? wk : (wsel == 2) ? wv : wp;
        dst = wbf + (size_t)wsel * NE * NE;
    }
    float4 f = ((const float4*)src)[off];
    short4 o;
    o.x = f2bf(f.x); o.y = f2bf(f.y); o.z = f2bf(f.z); o.w = f2bf(f.w);
    ((short4*)dst)[off] = o;
}

// ---------- shared GEMM mainloop: C[m,n] = sum_k A[m,k] * W[n,k] ----------
// 128x128 tile, BK=64, 256 threads = 4 waves (2x2), each wave 64x64 via 4x4 MFMAs.
DEVI void gemm_mainloop(const short* __restrict__ A, const short* __restrict__ W,
                        int m0, int n0, short* ldsA, short* ldsW, floatx4 (&acc)[4][4]) {
    const int tid  = threadIdx.x;
    const int lane = tid & 63;
    const int w    = tid >> 6;
    const int wm   = w >> 1, wn = w & 1;
    const int quad = lane >> 4, l15 = lane & 15;
    const int srow = lane >> 3, scol = (lane & 7) * 8;

    for (int i = 0; i < 4; ++i)
        for (int j = 0; j < 4; ++j)
            acc[i][j] = floatx4{0.f, 0.f, 0.f, 0.f};

    for (int kt = 0; kt < NE / 64; ++kt) {
        const int k0 = kt * 64;
        for (int c = 0; c < 4; ++c) {
            const int rb = w * 32 + c * 8;
            async16(A + (size_t)(m0 + rb + srow) * NE + k0 + scol, ldsA + rb * 64);
            async16(W + (size_t)(n0 + rb + srow) * NE + k0 + scol, ldsW + rb * 64);
        }
        __syncthreads();
        for (int ks = 0; ks < 2; ++ks) {
            short8 af[4], bf[4];
            for (int i = 0; i < 4; ++i)
                af[i] = *(const short8*)(ldsA + (wm * 64 + i * 16 + l15) * 64 + ks * 32 + quad * 8);
            for (int j = 0; j < 4; ++j)
                bf[j] = *(const short8*)(ldsW + (wn * 64 + j * 16 + l15) * 64 + ks * 32 + quad * 8);
            for (int i = 0; i < 4; ++i)
                for (int j = 0; j < 4; ++j)
                    acc[i][j] = __builtin_amdgcn_mfma_f32_16x16x32_bf16(af[i], bf[j], acc[i][j], 0, 0, 0);
        }
        __syncthreads();
    }
}

// ---------- QKV GEMM ----------
// z==0: q (pre-scaled by QSCALE), z==1: k — [B,H,T,HD].
// z==2: v written DIRECTLY TRANSPOSED as vt[bh][d][t] (short4 over 4 consecutive
// t from the C/D layout's r-dimension) — replaces the separate transpose_v
// kernel (R10 lesson: non-attn kernels+overhead = ~125us > attn; cheapest
// certain recovery is deleting a dispatch + 32MB of traffic).
__global__ __launch_bounds__(256) void gemm_qkv(const short* __restrict__ xbf,
                                                const short* __restrict__ wbf,
                                                const float* __restrict__ bq,
                                                const float* __restrict__ bk,
                                                const float* __restrict__ bv,
                                                short* __restrict__ qkv) {
    __shared__ short ldsA[128 * 64];
    __shared__ short ldsW[128 * 64];
    const int m0 = blockIdx.x * 128, n0 = blockIdx.y * 128, z = blockIdx.z;
    const short* W = wbf + (size_t)z * (NE * NE);
    const float* bias = (z == 0) ? bq : (z == 1) ? bk : bv;
    short* out = qkv + (size_t)z * (MTOT * NE);

    floatx4 acc[4][4];
    gemm_mainloop(xbf, W, m0, n0, ldsA, ldsW, acc);

    const int lane = threadIdx.x & 63, w = threadIdx.x >> 6;
    const int wm = w >> 1, wn = w & 1, quad = lane >> 4, l15 = lane & 15;
    if (z == 2) {
        // v -> vt[bh][d][t]: r=0..3 are 4 consecutive t -> one short4 store
        for (int j = 0; j < 4; ++j) {
            const int col = n0 + wn * 64 + j * 16 + l15;
            const float bz = bv[col];
            const int h = col >> 6, d = col & 63;
            for (int i = 0; i < 4; ++i) {
                const int row0 = m0 + wm * 64 + i * 16 + quad * 4;
                const int b = row0 >> 12, t0 = row0 & 4095;
                short4 o;
                o.x = f2bf(acc[i][j][0] + bz);
                o.y = f2bf(acc[i][j][1] + bz);
                o.z = f2bf(acc[i][j][2] + bz);
                o.w = f2bf(acc[i][j][3] + bz);
                *(short4*)&out[((size_t)(b * NH + h) * HD + d) * SEQ + t0] = o;
            }
        }
    } else {
        const float scale = (z == 0) ? QSCALE : 1.0f;
        for (int j = 0; j < 4; ++j) {
            const int col = n0 + wn * 64 + j * 16 + l15;
            const float bz = bias[col];
            const int h = col >> 6, d = col & 63;
            for (int i = 0; i < 4; ++i) {
                for (int r = 0; r < 4; ++r) {
                    const int row = m0 + wm * 64 + i * 16 + quad * 4 + r;
                    const int b = row >> 12, t = row & 4095;
                    const float v = (acc[i][j][r] + bz) * scale;
                    out[(((size_t)(b * NH + h)) * SEQ + t) * HD + d] = f2bf(v);
                }
            }
        }
    }
}

// ---------- projection GEMM: fp32 out [MTOT, NE] ----------
__global__ __launch_bounds__(256) void gemm_proj(const short* __restrict__ ybf,
                                                 const short* __restrict__ wp,
                                                 const float* __restrict__ bp,
                                                 float* __restrict__ out) {
    __shared__ short ldsA[128 * 64];
    __shared__ short ldsW[128 * 64];
    const int m0 = blockIdx.x * 128, n0 = blockIdx.y * 128;

    floatx4 acc[4][4];
    gemm_mainloop(ybf, wp, m0, n0, ldsA, ldsW, acc);

    const int lane = threadIdx.x & 63, w = threadIdx.x >> 6;
    const int wm = w >> 1, wn = w & 1, quad = lane >> 4, l15 = lane & 15;
    for (int j = 0; j < 4; ++j) {
        const int col = n0 + wn * 64 + j * 16 + l15;
        const float bz = bp[col];
        for (int i = 0; i < 4; ++i) {
            for (int r = 0; r < 4; ++r) {
                const int row = m0 + wm * 64 + i * 16 + quad * 4 + r;
                out[(size_t)row * NE + col] = acc[i][j][r] + bz;
            }
        }
    }
}

// ---------- flash attention (causal) ----------
// R5-verified structure (79us, 5-for-5 correct): grid 512, intra-block
// sel-pairing (bx, 63-bx) for CU balance + 2-block co-residency (R10 proved
// inter-block pairing halves occupancy: short partner dies early, window
// latency 1.2 -> 1.45-1.8us). Branch-free full windows, peeled diagonal
// (DOMASK), subtiles straight-line, K/V dbuf via async16, XOR-swizzled.
// P-path: f2bf + stride-72 LDS round-trip — the ONLY verified P-path; the
// in-register family (tr_read R7, swapped-QK R9) failed on HW and is shelved.
// P-pack MUST be f2bf (RNE): truncating pack failed 4-for-4. Do not retry.
// T5 setprio kept around MFMA clusters (m191 regime).
template<bool DOMASK>
DEVI void attn_subtile(const short* __restrict__ bK, const short* __restrict__ bV,
                       const short8 (&qfrag)[2], short* __restrict__ myP,
                       floatx4 (&O)[4], float (&lsum)[4],
                       const int p0, const int p1, const int quad, const int l15,
                       const int w) {
    short8 kf[2][4], vf[2][4];
#pragma unroll
    for (int n = 0; n < 4; ++n) {
        const int row = n * 16 + l15;
        kf[0][n] = *(const short8*)(bK + row * 64 + p0 * 8);
        kf[1][n] = *(const short8*)(bK + row * 64 + p1 * 8);
        vf[0][n] = *(const short8*)(bV + row * 64 + p0 * 8);
        vf[1][n] = *(const short8*)(bV + row * 64 + p1 * 8);
    }

    floatx4 S[4];
#pragma unroll
    for (int n = 0; n < 4; ++n) S[n] = floatx4{0.f, 0.f, 0.f, 0.f};
    __builtin_amdgcn_s_setprio(1);
#pragma unroll
    for (int ks = 0; ks < 2; ++ks)
#pragma unroll
        for (int n = 0; n < 4; ++n)
            S[n] = __builtin_amdgcn_mfma_f32_16x16x32_bf16(qfrag[ks], kf[ks][n], S[n], 0, 0, 0);
    __builtin_amdgcn_s_setprio(0);

    if (DOMASK) {
        // causal mask on the diagonal subtile (exp2(-3e38) = 0)
#pragma unroll
        for (int n = 0; n < 4; ++n)
#pragma unroll
            for (int r = 0; r < 4; ++r) {
                const int rowl = w * 16 + quad * 4 + r;
                const int coll = n * 16 + l15;
                if (coll > rowl) S[n][r] = -3.0e38f;
            }
    }

    // no-max softmax: P = exp2(S); deferred row-sum partials
#pragma unroll
    for (int n = 0; n < 4; ++n)
#pragma unroll
        for (int r = 0; r < 4; ++r)
            S[n][r] = __builtin_amdgcn_exp2f(S[n][r]);
#pragma unroll
    for (int r = 0; r < 4; ++r)
        lsum[r] += (S[0][r] + S[1][r]) + (S[2][r] + S[3][r]);

    // P (C/D layout) -> wave-private LDS (stride 72), RNE pack (f2bf).
#pragma unroll
    for (int n = 0; n < 4; ++n)
#pragma unroll
        for (int r = 0; r < 4; ++r)
            myP[(quad * 4 + r) * 72 + n * 16 + l15] = f2bf(S[n][r]);

    short8 pf[2];
#pragma unroll
    for (int ks = 0; ks < 2; ++ks)
        pf[ks] = *(const short8*)(myP + l15 * 72 + ks * 32 + quad * 8);

    // O += P @ V
    __builtin_amdgcn_s_setprio(1);
#pragma unroll
    for (int ks = 0; ks < 2; ++ks)
#pragma unroll
        for (int n = 0; n < 4; ++n)
            O[n] = __builtin_amdgcn_mfma_f32_16x16x32_bf16(pf[ks], vf[ks][n], O[n], 0, 0, 0);
    __builtin_amdgcn_s_setprio(0);
}

__global__ __launch_bounds__(256, 2) void attn(const short* __restrict__ q,
                                               const short* __restrict__ k,
                                               const short* __restrict__ vt,
                                               short* __restrict__ y) {
    const int id = blockIdx.x;                 // 0..511
    const int bx = id >> 4;                    // 0..31
    const int bh = ((id & 7) << 1) | ((id >> 3) & 1);
    const int tid = threadIdx.x, lane = tid & 63, w = tid >> 6;
    const int quad = lane >> 4, l15 = lane & 15;

    __shared__ short ldsK[2][2][64 * 64];   // [pipe][sub], swizzled
    __shared__ short ldsV[2][2][64 * 64];   // [pipe][sub], swizzled
    __shared__ short ldsP[4][16 * 72];      // per-wave P round-trip, stride 72

    const short* K  = k  + (size_t)bh * (SEQ * HD);
    const short* VT = vt + (size_t)bh * (HD * SEQ);
    short* myP = (short*)ldsP[w];
    const int b = bh >> 3, h = bh & 7;

    // staging: lane l of chunk c covers row j = c*8 + (l>>3), phys block l&7,
    // logical block lb = ((l&7) - (l>>3)) & 7.
    const int lb   = ((lane & 7) - (lane >> 3)) & 7;
    const int jrow = lane >> 3;
    // fragment reads: row = n*16+l15, logical block ks*4+quad ->
    // phys = (quad + (l15&7)) & 7  xor (ks*4)
    const int p0 = (quad + (l15 & 7)) & 7;
    const int p1 = p0 ^ 4;

    for (int sel = 0; sel < 2; ++sel) {
        const int qt = sel ? (SEQ / 64 - 1 - bx) : bx;
        const short* Q = q + (size_t)bh * (SEQ * HD) + (size_t)qt * 64 * HD;

        short8 qfrag[2];
#pragma unroll
        for (int ks = 0; ks < 2; ++ks)
            qfrag[ks] = *(const short8*)&Q[(w * 16 + l15) * HD + ks * 32 + quad * 8];

        floatx4 O[4];
        float lsum[4];
#pragma unroll
        for (int n = 0; n < 4; ++n) O[n] = floatx4{0.f, 0.f, 0.f, 0.f};
#pragma unroll
        for (int r = 0; r < 4; ++r) lsum[r] = 0.f;

        const int npair = (qt >> 1) + 1;    // key windows; window p holds jt=2p,2p+1
        // staging is unconditional everywhere: max staged js = 2*npair-1 <= 63
        // for all qt (proven), so no OOB; windows whose jt exceeds qt are staged
        // but never computed.

        // protect buffers from the previous sel's readers, then stage pair 0
        __syncthreads();
#pragma unroll
        for (int s = 0; s < 2; ++s) {
            const short* Kt = K + (size_t)s * 64 * HD;
            const short* Vc = VT + s * 64;
#pragma unroll
            for (int c2 = 0; c2 < 2; ++c2) {
                const int chunk = w * 2 + c2;
                const int j = chunk * 8 + jrow;
                async16(Kt + (size_t)j * HD + lb * 8, ldsK[0][s] + chunk * 512);
                async16(Vc + (size_t)j * SEQ + lb * 8, ldsV[0][s] + chunk * 512);
            }
        }

        // ---- main loop: FULL windows only (branch-free, mask-free) ----
        for (int p = 0; p + 1 < npair; ++p) {
            __syncthreads();                // drains the async stage of this pair
            const int pipe = p & 1, nx = pipe ^ 1;

            // stage pair p+1 into the other pipe (lands during this pair's compute)
#pragma unroll
            for (int s = 0; s < 2; ++s) {
                const int js = 2 * (p + 1) + s;
                const short* Kt = K + (size_t)js * 64 * HD;
                const short* Vc = VT + js * 64;
#pragma unroll
                for (int c2 = 0; c2 < 2; ++c2) {
                    const int chunk = w * 2 + c2;
                    const int j = chunk * 8 + jrow;
                    async16(Kt + (size_t)j * HD + lb * 8, ldsK[nx][s] + chunk * 512);
                    async16(Vc + (size_t)j * SEQ + lb * 8, ldsV[nx][s] + chunk * 512);
                }
            }

            // two subtiles, straight-line: scheduler interleaves the chains
            attn_subtile<false>(ldsK[pipe][0], ldsV[pipe][0], qfrag, myP, O, lsum,
                                p0, p1, quad, l15, w);
            attn_subtile<false>(ldsK[pipe][1], ldsV[pipe][1], qfrag, myP, O, lsum,
                                p0, p1, quad, l15, w);
        }

        // ---- epilogue window p = npair-1 (holds the diagonal) ----
        {
            __syncthreads();
            const int ep = (npair - 1) & 1;
            if (qt & 1) {
                // jt = qt-1 (full) then jt = qt (diagonal)
                attn_subtile<false>(ldsK[ep][0], ldsV[ep][0], qfrag, myP, O, lsum,
                                    p0, p1, quad, l15, w);
                attn_subtile<true >(ldsK[ep][1], ldsV[ep][1], qfrag, myP, O, lsum,
                                    p0, p1, quad, l15, w);
            } else {
                // jt = qt (diagonal); sub1 staged but skipped
                attn_subtile<true >(ldsK[ep][0], ldsV[ep][0], qfrag, myP, O, lsum,
                                    p0, p1, quad, l15, w);
            }
        }

        // reduce row-sum partials across the 16-lane row group
#pragma unroll
        for (int r = 0; r < 4; ++r) {
#pragma unroll
            for (int off = 1; off < 16; off <<= 1)
                lsum[r] += __shfl_xor(lsum[r], off, 64);
        }

        // epilogue: y[b, t, h*64+d] bf16, normalized by lsum
#pragma unroll
        for (int r = 0; r < 4; ++r) {
            const float inv = 1.0f / lsum[r];
            const int t = qt * 64 + w * 16 + quad * 4 + r;
#pragma unroll
            for (int n = 0; n < 4; ++n) {
                const int col = h * 64 + n * 16 + l15;
                y[((size_t)(b * SEQ + t)) * NE + col] = f2bf(O[n][r] * inv);
            }
        }
    }
}

// ---------- host launch ----------
extern "C" void kernel_launch(void* const* d_in, const int* in_sizes, int n_in,
                              void* d_out, int out_size, void* d_ws, size_t ws_size,
                              hipStream_t stream) {
    const float* x  = (const float*)d_in[0];
    const float* Wq = (const float*)d_in[3];
    const float* bq = (const float*)d_in[4];
    const float* Wk = (const float*)d_in[5];
    const float* bk = (const float*)d_in[6];
    const float* Wv = (const float*)d_in[7];
    const float* bv = (const float*)d_in[8];
    const float* Wp = (const float*)d_in[9];
    const float* bp = (const float*)d_in[10];
    float* out = (float*)d_out;

    // ws layout (shorts) with live-range aliasing — peak 17.8M shorts = 35.6 MB
    // gemm_qkv z==2 writes v DIRECTLY transposed into the third qkv slot
    // (vtb); attn output yb aliases xbf (dead after gemm_qkv).
    short* ws   = (short*)d_ws;
    short* xbf  = ws;                           // 8192*512 shorts
    short* wbf  = xbf + (size_t)MTOT * NE;      // 4 * 512*512
    short* qb   = wbf + 4 * (size_t)NE * NE;    // q  [B,H,T,HD]  (pre-scaled)
    short* kb   = qb + (size_t)MTOT * NE;       // k  [B,H,T,HD]
    short* vtb  = kb + (size_t)MTOT * NE;       // v^T [B,H,HD,T] (from gemm_qkv)
    short* yb   = xbf;                          // y   [B,T,C]    (aliases xbf)

    // fused conversion: x + 4 weights, one dispatch (5120 blocks, exact cover)
    cvt_all<<<dim3((MTOT * NE / 4 + 4 * NE * NE / 4) / 256), 256, 0, stream>>>(
        x, Wq, Wk, Wv, Wp, xbf, wbf);

    gemm_qkv<<<dim3(MTOT / 128, NE / 128, 3), 256, 0, stream>>>(xbf, wbf, bq, bk, bv, qb);

    attn<<<dim3(512), 256, 0, stream>>>(qb, kb, vtb, yb);

    gemm_proj<<<dim3(MTOT / 128, NE / 128), 256, 0, stream>>>(yb, wbf + 3 * (size_t)NE * NE, bp, out);
}

// Round 12
// 196.873 us; speedup vs baseline: 1.3909x; 1.0034x over previous
//
#include <hip/hip_runtime.h>
#include <math.h>

// ---------- types ----------
using short8  = __attribute__((ext_vector_type(8))) short;   // 8 x bf16 (4 VGPRs)
using floatx4 = __attribute__((ext_vector_type(4))) float;   // MFMA accumulator

#define DEVI __device__ __forceinline__

// Problem constants
#define BATCH 2
#define SEQ   4096
#define NE    512      // n_embd
#define NH    8
#define HD    64
#define MTOT  8192     // BATCH*SEQ

// softmax scale with log2(e) folded: (1/sqrt(64)) * log2(e)
#define QSCALE 0.18033688011112042f

DEVI short f2bf(float f) {
    unsigned u = __builtin_bit_cast(unsigned, f);
    unsigned r = (u + 0x7fffu + ((u >> 16) & 1u)) >> 16;   // RNE
    return (short)r;
}

DEVI void async16(const void* g, void* l) {
    __builtin_amdgcn_global_load_lds(
        (const __attribute__((address_space(1))) void*)g,
        (__attribute__((address_space(3))) void*)l, 16, 0, 0);
}

// ---------- fused fp32 -> bf16 conversion (x + 4 weights, one dispatch) ----------
// float4-region map: [0, 1048576) = x ; then 65536 per weight (NE*NE/4 = 65536).
__global__ __launch_bounds__(256) void cvt_all(const float* __restrict__ x,
                                               const float* __restrict__ wq,
                                               const float* __restrict__ wk,
                                               const float* __restrict__ wv,
                                               const float* __restrict__ wp,
                                               short* __restrict__ xbf,
                                               short* __restrict__ wbf) {
    int i = blockIdx.x * 256 + threadIdx.x;          // 0 .. 1310719 (exact)
    const float* src; short* dst; int off;
    if (i < MTOT * NE / 4) {
        src = x; dst = xbf; off = i;
    } else {
        int j = i - MTOT * NE / 4;
        int wsel = j >> 16;                          // 65536 float4 per weight
        off = j & 65535;
        src = (wsel == 0) ? wq : (wsel == 1) ? wk : (wsel == 2) ? wv : wp;
        dst = wbf + (size_t)wsel * NE * NE;
    }
    float4 f = ((const float4*)src)[off];
    short4 o;
    o.x = f2bf(f.x); o.y = f2bf(f.y); o.z = f2bf(f.z); o.w = f2bf(f.w);
    ((short4*)dst)[off] = o;
}

// ---------- shared GEMM mainloop: C[m,n] = sum_k A[m,k] * W[n,k] ----------
// 128x128 tile, BK=64, 256 threads = 4 waves (2x2), each wave 64x64 via 4x4 MFMAs.
DEVI void gemm_mainloop(const short* __restrict__ A, const short* __restrict__ W,
                        int m0, int n0, short* ldsA, short* ldsW, floatx4 (&acc)[4][4]) {
    const int tid  = threadIdx.x;
    const int lane = tid & 63;
    const int w    = tid >> 6;
    const int wm   = w >> 1, wn = w & 1;
    const int quad = lane >> 4, l15 = lane & 15;
    const int srow = lane >> 3, scol = (lane & 7) * 8;

    for (int i = 0; i < 4; ++i)
        for (int j = 0; j < 4; ++j)
            acc[i][j] = floatx4{0.f, 0.f, 0.f, 0.f};

    for (int kt = 0; kt < NE / 64; ++kt) {
        const int k0 = kt * 64;
        for (int c = 0; c < 4; ++c) {
            const int rb = w * 32 + c * 8;
            async16(A + (size_t)(m0 + rb + srow) * NE + k0 + scol, ldsA + rb * 64);
            async16(W + (size_t)(n0 + rb + srow) * NE + k0 + scol, ldsW + rb * 64);
        }
        __syncthreads();
        for (int ks = 0; ks < 2; ++ks) {
            short8 af[4], bf[4];
            for (int i = 0; i < 4; ++i)
                af[i] = *(const short8*)(ldsA + (wm * 64 + i * 16 + l15) * 64 + ks * 32 + quad * 8);
            for (int j = 0; j < 4; ++j)
                bf[j] = *(const short8*)(ldsW + (wn * 64 + j * 16 + l15) * 64 + ks * 32 + quad * 8);
            for (int i = 0; i < 4; ++i)
                for (int j = 0; j < 4; ++j)
                    acc[i][j] = __builtin_amdgcn_mfma_f32_16x16x32_bf16(af[i], bf[j], acc[i][j], 0, 0, 0);
        }
        __syncthreads();
    }
}

// ---------- QKV GEMM ----------
// z==0: q (pre-scaled by QSCALE), z==1: k — [B,H,T,HD].
// z==2: v written DIRECTLY TRANSPOSED as vt[bh][d][t].
// R12: ALL epilogues staged through LDS for coalesced stores (R10->R11 delta
// proved the scattered vt short4 stores cost ~+12us; q/k 2B scalar stores are
// the milder version). Mainloop's final barrier frees ldsA/ldsW; one
// 128x(stride 132) short tile (33.8KB) stages the tile, then short8 stores:
//   z0/1: tile[t][d] -> 1KB-contiguous runs per head-row group
//   z2  : tile[d][t] -> dense 256B segments per d-row
// Stride 132 puts the 4 quads on disjoint bank groups for the scalar writes.
__global__ __launch_bounds__(256) void gemm_qkv(const short* __restrict__ xbf,
                                                const short* __restrict__ wbf,
                                                const float* __restrict__ bq,
                                                const float* __restrict__ bk,
                                                const float* __restrict__ bv,
                                                short* __restrict__ qkv) {
    __shared__ short lds[128 * 132];        // 33792 B; mainloop carves A/W from it
    short* ldsA = lds;                      // 128*64
    short* ldsW = lds + 128 * 64;           // 128*64
    const int m0 = blockIdx.x * 128, n0 = blockIdx.y * 128, z = blockIdx.z;
    const short* W = wbf + (size_t)z * (NE * NE);
    short* out = qkv + (size_t)z * (MTOT * NE);

    floatx4 acc[4][4];
    gemm_mainloop(xbf, W, m0, n0, ldsA, ldsW, acc);
    // mainloop ends with __syncthreads(): all LDS reads done -> safe to reuse.

    const int tid = threadIdx.x;
    const int lane = tid & 63, w = tid >> 6;
    const int wm = w >> 1, wn = w & 1, quad = lane >> 4, l15 = lane & 15;
    const int b = m0 >> 12, t0 = m0 & 4095;   // tiles never straddle batch

    if (z == 2) {
        // ---- stage tile[d][t], stride 132 (short4 along t) ----
        for (int j = 0; j < 4; ++j) {
            const int dl = wn * 64 + j * 16 + l15;
            const float bz = bv[n0 + dl];
            for (int i = 0; i < 4; ++i) {
                const int tl0 = wm * 64 + i * 16 + quad * 4;
                short4 o;
                o.x = f2bf(acc[i][j][0] + bz);
                o.y = f2bf(acc[i][j][1] + bz);
                o.z = f2bf(acc[i][j][2] + bz);
                o.w = f2bf(acc[i][j][3] + bz);
                *(short4*)&lds[dl * 132 + tl0] = o;
            }
        }
        __syncthreads();
        // ---- coalesced store: wave = 4 dense 256B d-rows per pass ----
        const int tc = tid & 15, dr = tid >> 4;       // tc: 8-t chunk, dr: 0..15
        for (int p = 0; p < 8; ++p) {
            const int dl = p * 16 + dr;
            const int colg = n0 + dl;
            const int hg = colg >> 6, d = colg & 63;
            short8 v = *(short8*)&lds[dl * 132 + tc * 8];
            *(short8*)&out[((size_t)(b * NH + hg) * HD + d) * SEQ + t0 + tc * 8] = v;
        }
    } else {
        const float* bias = (z == 0) ? bq : bk;
        const float scale = (z == 0) ? QSCALE : 1.0f;
        // ---- stage tile[t][d], stride 132 (scalar writes, conflict-free) ----
        for (int j = 0; j < 4; ++j) {
            const int dl = wn * 64 + j * 16 + l15;
            const float bz = bias[n0 + dl];
            for (int i = 0; i < 4; ++i) {
                for (int r = 0; r < 4; ++r) {
                    const int tl = wm * 64 + i * 16 + quad * 4 + r;
                    lds[tl * 132 + dl] = f2bf((acc[i][j][r] + bz) * scale);
                }
            }
        }
        __syncthreads();
        // ---- coalesced store: 2 heads/block; wave = 1KB contiguous runs ----
        const int hsel = tid >> 7;                    // 0/1: which head half
        const int dc = tid & 7, trow = (tid >> 3) & 15;
        const int hg = (n0 + hsel * 64) >> 6;
        short* outbase = out + ((size_t)(b * NH + hg) * SEQ + t0) * HD;
        for (int p = 0; p < 8; ++p) {
            const int tl = p * 16 + trow;
            short8 v = *(short8*)&lds[tl * 132 + hsel * 64 + dc * 8];
            *(short8*)&outbase[(size_t)tl * HD + dc * 8] = v;
        }
    }
}

// ---------- projection GEMM: fp32 out [MTOT, NE] ----------
// (stores are already full-cache-line coalesced: 4x64B segments per instr)
__global__ __launch_bounds__(256) void gemm_proj(const short* __restrict__ ybf,
                                                 const short* __restrict__ wp,
                                                 const float* __restrict__ bp,
                                                 float* __restrict__ out) {
    __shared__ short ldsA[128 * 64];
    __shared__ short ldsW[128 * 64];
    const int m0 = blockIdx.x * 128, n0 = blockIdx.y * 128;

    floatx4 acc[4][4];
    gemm_mainloop(ybf, wp, m0, n0, ldsA, ldsW, acc);

    const int lane = threadIdx.x & 63, w = threadIdx.x >> 6;
    const int wm = w >> 1, wn = w & 1, quad = lane >> 4, l15 = lane & 15;
    for (int j = 0; j < 4; ++j) {
        const int col = n0 + wn * 64 + j * 16 + l15;
        const float bz = bp[col];
        for (int i = 0; i < 4; ++i) {
            for (int r = 0; r < 4; ++r) {
                const int row = m0 + wm * 64 + i * 16 + quad * 4 + r;
                out[(size_t)row * NE + col] = acc[i][j][r] + bz;
            }
        }
    }
}

// ---------- flash attention (causal) ----------
// R5-verified structure (77-79us, 6-for-6 correct): grid 512, intra-block
// sel-pairing (bx, 63-bx) for CU balance + 2-block co-residency (R10 proved
// inter-block pairing halves occupancy). Branch-free full windows, peeled
// diagonal (DOMASK), subtiles straight-line, K/V dbuf via async16, swizzled.
// P-path: f2bf + stride-72 LDS round-trip — the ONLY verified P-path; the
// in-register family (tr_read R7, swapped-QK R9) failed on HW and is shelved.
// P-pack MUST be f2bf (RNE): truncating pack failed 4-for-4. Do not retry.
// T5 setprio kept around MFMA clusters (m191 regime).
template<bool DOMASK>
DEVI void attn_subtile(const short* __restrict__ bK, const short* __restrict__ bV,
                       const short8 (&qfrag)[2], short* __restrict__ myP,
                       floatx4 (&O)[4], float (&lsum)[4],
                       const int p0, const int p1, const int quad, const int l15,
                       const int w) {
    short8 kf[2][4], vf[2][4];
#pragma unroll
    for (int n = 0; n < 4; ++n) {
        const int row = n * 16 + l15;
        kf[0][n] = *(const short8*)(bK + row * 64 + p0 * 8);
        kf[1][n] = *(const short8*)(bK + row * 64 + p1 * 8);
        vf[0][n] = *(const short8*)(bV + row * 64 + p0 * 8);
        vf[1][n] = *(const short8*)(bV + row * 64 + p1 * 8);
    }

    floatx4 S[4];
#pragma unroll
    for (int n = 0; n < 4; ++n) S[n] = floatx4{0.f, 0.f, 0.f, 0.f};
    __builtin_amdgcn_s_setprio(1);
#pragma unroll
    for (int ks = 0; ks < 2; ++ks)
#pragma unroll
        for (int n = 0; n < 4; ++n)
            S[n] = __builtin_amdgcn_mfma_f32_16x16x32_bf16(qfrag[ks], kf[ks][n], S[n], 0, 0, 0);
    __builtin_amdgcn_s_setprio(0);

    if (DOMASK) {
        // causal mask on the diagonal subtile (exp2(-3e38) = 0)
#pragma unroll
        for (int n = 0; n < 4; ++n)
#pragma unroll
            for (int r = 0; r < 4; ++r) {
                const int rowl = w * 16 + quad * 4 + r;
                const int coll = n * 16 + l15;
                if (coll > rowl) S[n][r] = -3.0e38f;
            }
    }

    // no-max softmax: P = exp2(S); deferred row-sum partials
#pragma unroll
    for (int n = 0; n < 4; ++n)
#pragma unroll
        for (int r = 0; r < 4; ++r)
            S[n][r] = __builtin_amdgcn_exp2f(S[n][r]);
#pragma unroll
    for (int r = 0; r < 4; ++r)
        lsum[r] += (S[0][r] + S[1][r]) + (S[2][r] + S[3][r]);

    // P (C/D layout) -> wave-private LDS (stride 72), RNE pack (f2bf).
#pragma unroll
    for (int n = 0; n < 4; ++n)
#pragma unroll
        for (int r = 0; r < 4; ++r)
            myP[(quad * 4 + r) * 72 + n * 16 + l15] = f2bf(S[n][r]);

    short8 pf[2];
#pragma unroll
    for (int ks = 0; ks < 2; ++ks)
        pf[ks] = *(const short8*)(myP + l15 * 72 + ks * 32 + quad * 8);

    // O += P @ V
    __builtin_amdgcn_s_setprio(1);
#pragma unroll
    for (int ks = 0; ks < 2; ++ks)
#pragma unroll
        for (int n = 0; n < 4; ++n)
            O[n] = __builtin_amdgcn_mfma_f32_16x16x32_bf16(pf[ks], vf[ks][n], O[n], 0, 0, 0);
    __builtin_amdgcn_s_setprio(0);
}

__global__ __launch_bounds__(256, 2) void attn(const short* __restrict__ q,
                                               const short* __restrict__ k,
                                               const short* __restrict__ vt,
                                               short* __restrict__ y) {
    const int id = blockIdx.x;                 // 0..511
    const int bx = id >> 4;                    // 0..31
    const int bh = ((id & 7) << 1) | ((id >> 3) & 1);
    const int tid = threadIdx.x, lane = tid & 63, w = tid >> 6;
    const int quad = lane >> 4, l15 = lane & 15;

    __shared__ short ldsK[2][2][64 * 64];   // [pipe][sub], swizzled
    __shared__ short ldsV[2][2][64 * 64];   // [pipe][sub], swizzled
    __shared__ short ldsP[4][16 * 72];      // per-wave P round-trip, stride 72

    const short* K  = k  + (size_t)bh * (SEQ * HD);
    const short* VT = vt + (size_t)bh * (HD * SEQ);
    short* myP = (short*)ldsP[w];
    const int b = bh >> 3, h = bh & 7;

    // staging: lane l of chunk c covers row j = c*8 + (l>>3), phys block l&7,
    // logical block lb = ((l&7) - (l>>3)) & 7.
    const int lb   = ((lane & 7) - (lane >> 3)) & 7;
    const int jrow = lane >> 3;
    // fragment reads: row = n*16+l15, logical block ks*4+quad ->
    // phys = (quad + (l15&7)) & 7  xor (ks*4)
    const int p0 = (quad + (l15 & 7)) & 7;
    const int p1 = p0 ^ 4;

    for (int sel = 0; sel < 2; ++sel) {
        const int qt = sel ? (SEQ / 64 - 1 - bx) : bx;
        const short* Q = q + (size_t)bh * (SEQ * HD) + (size_t)qt * 64 * HD;

        short8 qfrag[2];
#pragma unroll
        for (int ks = 0; ks < 2; ++ks)
            qfrag[ks] = *(const short8*)&Q[(w * 16 + l15) * HD + ks * 32 + quad * 8];

        floatx4 O[4];
        float lsum[4];
#pragma unroll
        for (int n = 0; n < 4; ++n) O[n] = floatx4{0.f, 0.f, 0.f, 0.f};
#pragma unroll
        for (int r = 0; r < 4; ++r) lsum[r] = 0.f;

        const int npair = (qt >> 1) + 1;    // key windows; window p holds jt=2p,2p+1
        // staging is unconditional everywhere: max staged js = 2*npair-1 <= 63
        // for all qt (proven), so no OOB; windows whose jt exceeds qt are staged
        // but never computed.

        // protect buffers from the previous sel's readers, then stage pair 0
        __syncthreads();
#pragma unroll
        for (int s = 0; s < 2; ++s) {
            const short* Kt = K + (size_t)s * 64 * HD;
            const short* Vc = VT + s * 64;
#pragma unroll
            for (int c2 = 0; c2 < 2; ++c2) {
                const int chunk = w * 2 + c2;
                const int j = chunk * 8 + jrow;
                async16(Kt + (size_t)j * HD + lb * 8, ldsK[0][s] + chunk * 512);
                async16(Vc + (size_t)j * SEQ + lb * 8, ldsV[0][s] + chunk * 512);
            }
        }

        // ---- main loop: FULL windows only (branch-free, mask-free) ----
        for (int p = 0; p + 1 < npair; ++p) {
            __syncthreads();                // drains the async stage of this pair
            const int pipe = p & 1, nx = pipe ^ 1;

            // stage pair p+1 into the other pipe (lands during this pair's compute)
#pragma unroll
            for (int s = 0; s < 2; ++s) {
                const int js = 2 * (p + 1) + s;
                const short* Kt = K + (size_t)js * 64 * HD;
                const short* Vc = VT + js * 64;
#pragma unroll
                for (int c2 = 0; c2 < 2; ++c2) {
                    const int chunk = w * 2 + c2;
                    const int j = chunk * 8 + jrow;
                    async16(Kt + (size_t)j * HD + lb * 8, ldsK[nx][s] + chunk * 512);
                    async16(Vc + (size_t)j * SEQ + lb * 8, ldsV[nx][s] + chunk * 512);
                }
            }

            // two subtiles, straight-line: scheduler interleaves the chains
            attn_subtile<false>(ldsK[pipe][0], ldsV[pipe][0], qfrag, myP, O, lsum,
                                p0, p1, quad, l15, w);
            attn_subtile<false>(ldsK[pipe][1], ldsV[pipe][1], qfrag, myP, O, lsum,
                                p0, p1, quad, l15, w);
        }

        // ---- epilogue window p = npair-1 (holds the diagonal) ----
        {
            __syncthreads();
            const int ep = (npair - 1) & 1;
            if (qt & 1) {
                // jt = qt-1 (full) then jt = qt (diagonal)
                attn_subtile<false>(ldsK[ep][0], ldsV[ep][0], qfrag, myP, O, lsum,
                                    p0, p1, quad, l15, w);
                attn_subtile<true >(ldsK[ep][1], ldsV[ep][1], qfrag, myP, O, lsum,
                                    p0, p1, quad, l15, w);
            } else {
                // jt = qt (diagonal); sub1 staged but skipped
                attn_subtile<true >(ldsK[ep][0], ldsV[ep][0], qfrag, myP, O, lsum,
                                    p0, p1, quad, l15, w);
            }
        }

        // reduce row-sum partials across the 16-lane row group
#pragma unroll
        for (int r = 0; r < 4; ++r) {
#pragma unroll
            for (int off = 1; off < 16; off <<= 1)
                lsum[r] += __shfl_xor(lsum[r], off, 64);
        }

        // epilogue: y[b, t, h*64+d] bf16, normalized by lsum
#pragma unroll
        for (int r = 0; r < 4; ++r) {
            const float inv = 1.0f / lsum[r];
            const int t = qt * 64 + w * 16 + quad * 4 + r;
#pragma unroll
            for (int n = 0; n < 4; ++n) {
                const int col = h * 64 + n * 16 + l15;
                y[((size_t)(b * SEQ + t)) * NE + col] = f2bf(O[n][r] * inv);
            }
        }
    }
}

// ---------- host launch ----------
extern "C" void kernel_launch(void* const* d_in, const int* in_sizes, int n_in,
                              void* d_out, int out_size, void* d_ws, size_t ws_size,
                              hipStream_t stream) {
    const float* x  = (const float*)d_in[0];
    const float* Wq = (const float*)d_in[3];
    const float* bq = (const float*)d_in[4];
    const float* Wk = (const float*)d_in[5];
    const float* bk = (const float*)d_in[6];
    const float* Wv = (const float*)d_in[7];
    const float* bv = (const float*)d_in[8];
    const float* Wp = (const float*)d_in[9];
    const float* bp = (const float*)d_in[10];
    float* out = (float*)d_out;

    // ws layout (shorts) with live-range aliasing — peak 17.8M shorts = 35.6 MB
    // gemm_qkv z==2 writes v DIRECTLY transposed into the third qkv slot
    // (vtb); attn output yb aliases xbf (dead after gemm_qkv).
    short* ws   = (short*)d_ws;
    short* xbf  = ws;                           // 8192*512 shorts
    short* wbf  = xbf + (size_t)MTOT * NE;      // 4 * 512*512
    short* qb   = wbf + 4 * (size_t)NE * NE;    // q  [B,H,T,HD]  (pre-scaled)
    short* kb   = qb + (size_t)MTOT * NE;       // k  [B,H,T,HD]
    short* vtb  = kb + (size_t)MTOT * NE;       // v^T [B,H,HD,T] (from gemm_qkv)
    short* yb   = xbf;                          // y   [B,T,C]    (aliases xbf)

    // fused conversion: x + 4 weights, one dispatch (5120 blocks, exact cover)
    cvt_all<<<dim3((MTOT * NE / 4 + 4 * NE * NE / 4) / 256), 256, 0, stream>>>(
        x, Wq, Wk, Wv, Wp, xbf, wbf);

    gemm_qkv<<<dim3(MTOT / 128, NE / 128, 3), 256, 0, stream>>>(xbf, wbf, bq, bk, bv, qb);

    attn<<<dim3(512), 256, 0, stream>>>(qb, kb, vtb, yb);

    gemm_proj<<<dim3(MTOT / 128, NE / 128), 256, 0, stream>>>(yb, wbf + 3 * (size_t)NE * NE, bp, out);
}